// Round 3
// baseline (175.487 us; speedup 1.0000x reference)
//
#include <hip/hip_runtime.h>

// 2-level 2D Haar DWT, fused, one 4x8 input patch per thread (2 tiles wide).
// x: (96, 512, 512) fp32.
// History: persistent/depth-1 (60.9us, 12 waves/CU) == full-grid (60.0us,
// 18.6 waves/CU) == +NT stores (~59us): neither occupancy nor L3 pollution is
// the limiter. Theory: per-wave read MLP. Waves had only 4KB of loads in
// flight and a low issue duty cycle; reads ran at 1.7 TB/s while pure-write
// fill hits 6.8 TB/s at 9% occupancy. This version issues 8 independent 16B
// loads up-front (2x in-flight read bytes per wave) and halves store-instr
// count via 16B level-1 stores. Per-element arithmetic identical to reference
// (W-axis first, then H-axis, *KINV at each stage).
// Out layout: a2,h2,v2,d2 (each 96*128*128), then h1,v1,d1 (each 96*256*256).

#define KINV 0.7071067811865476f

typedef float v4f __attribute__((ext_vector_type(4)));
typedef float v2f __attribute__((ext_vector_type(2)));

// One 4x4 half-patch -> level-1 quads. b[k] = row k (cols 0..3 in x,y,z,w).
// Quad (i,j): rows 2i,2i+1, cols 2j,2j+1. Filter along W first, then H.
#define QUADS(b, aa, da, ad, dd)                                          \
    do {                                                                  \
        _Pragma("unroll")                                                 \
        for (int i = 0; i < 2; ++i) {                                     \
            const float q00 = b[2*i].x,   q01 = b[2*i].y;                 \
            const float q02 = b[2*i].z,   q03 = b[2*i].w;                 \
            const float q10 = b[2*i+1].x, q11 = b[2*i+1].y;               \
            const float q12 = b[2*i+1].z, q13 = b[2*i+1].w;               \
            {                                                             \
                const float sA = (q00 + q01) * KINV;                      \
                const float sB = (q10 + q11) * KINV;                      \
                const float dA = (q00 - q01) * KINV;                      \
                const float dB = (q10 - q11) * KINV;                      \
                aa[i][0] = (sA + sB) * KINV;                              \
                da[i][0] = (sA - sB) * KINV;                              \
                ad[i][0] = (dA + dB) * KINV;                              \
                dd[i][0] = (dA - dB) * KINV;                              \
            }                                                             \
            {                                                             \
                const float sA = (q02 + q03) * KINV;                      \
                const float sB = (q12 + q13) * KINV;                      \
                const float dA = (q02 - q03) * KINV;                      \
                const float dB = (q12 - q13) * KINV;                      \
                aa[i][1] = (sA + sB) * KINV;                              \
                da[i][1] = (sA - sB) * KINV;                              \
                ad[i][1] = (dA + dB) * KINV;                              \
                dd[i][1] = (dA - dB) * KINV;                              \
            }                                                             \
        }                                                                 \
    } while (0)

__global__ __launch_bounds__(256, 4) void haar2_fused_kernel(
    const float* __restrict__ x, float* __restrict__ out, int nimg)
{
    const int tid = blockIdx.x * blockDim.x + threadIdx.x; // 0 .. nimg*8192-1
    const int cx  = tid & 63;           // 8-col patch index (lane-fast)
    const int r2  = (tid >> 6) & 127;   // level-2 row
    const int img = tid >> 13;          // 0..95

    const int row0 = r2 * 4;
    const int col0 = cx * 8;

    const size_t n2 = (size_t)nimg * 128 * 128;
    const size_t n1 = (size_t)nimg * 256 * 256;
    float* a2o = out;
    float* h2o = out + n2;
    float* v2o = out + 2 * n2;
    float* d2o = out + 3 * n2;
    float* h1o = out + 4 * n2;
    float* v1o = h1o + n1;
    float* d1o = h1o + 2 * n1;

    // Issue ALL 8 independent 16B loads before any consumption: 8KB/wave in
    // flight. bA = cols 0..3 of the patch, bB = cols 4..7.
    const size_t in_base = (size_t)img * (512 * 512) + (size_t)row0 * 512 + col0;
    v4f bA[4], bB[4];
    #pragma unroll
    for (int k = 0; k < 4; ++k) {
        bA[k] = *reinterpret_cast<const v4f*>(x + in_base + (size_t)k * 512);
        bB[k] = *reinterpret_cast<const v4f*>(x + in_base + (size_t)k * 512 + 4);
    }

    // Level 1, left half (overlaps with bB still in flight: waitcnt vmcnt(4)).
    float aaL[2][2], daL[2][2], adL[2][2], ddL[2][2];
    QUADS(bA, aaL, daL, adL, ddL);
    // Level 1, right half.
    float aaR[2][2], daR[2][2], adR[2][2], ddR[2][2];
    QUADS(bB, aaR, daR, adR, ddR);

    // Level-1 detail stores: one v4f per stream per row (coalesced 1KB/wave),
    // nontemporal (never re-read).
    const size_t img1 = (size_t)img * 256 * 256;
    #pragma unroll
    for (int i = 0; i < 2; ++i) {
        const size_t off = img1 + (size_t)(2 * r2 + i) * 256 + 4 * cx;
        __builtin_nontemporal_store((v4f){daL[i][0], daL[i][1], daR[i][0], daR[i][1]},
                                    reinterpret_cast<v4f*>(h1o + off));
        __builtin_nontemporal_store((v4f){adL[i][0], adL[i][1], adR[i][0], adR[i][1]},
                                    reinterpret_cast<v4f*>(v1o + off));
        __builtin_nontemporal_store((v4f){ddL[i][0], ddL[i][1], ddR[i][0], ddR[i][1]},
                                    reinterpret_cast<v4f*>(d1o + off));
    }

    // Level 2 from the two aa quads (left -> col 2cx, right -> col 2cx+1).
    const float s0L = (aaL[0][0] + aaL[0][1]) * KINV;
    const float d0L = (aaL[0][0] - aaL[0][1]) * KINV;
    const float s1L = (aaL[1][0] + aaL[1][1]) * KINV;
    const float d1L = (aaL[1][0] - aaL[1][1]) * KINV;
    const float s0R = (aaR[0][0] + aaR[0][1]) * KINV;
    const float d0R = (aaR[0][0] - aaR[0][1]) * KINV;
    const float s1R = (aaR[1][0] + aaR[1][1]) * KINV;
    const float d1R = (aaR[1][0] - aaR[1][1]) * KINV;

    const size_t off2 = (size_t)img * 128 * 128 + (size_t)r2 * 128 + 2 * cx;
    __builtin_nontemporal_store((v2f){(s0L + s1L) * KINV, (s0R + s1R) * KINV},
                                reinterpret_cast<v2f*>(a2o + off2));
    __builtin_nontemporal_store((v2f){(s0L - s1L) * KINV, (s0R - s1R) * KINV},
                                reinterpret_cast<v2f*>(h2o + off2));
    __builtin_nontemporal_store((v2f){(d0L + d1L) * KINV, (d0R + d1R) * KINV},
                                reinterpret_cast<v2f*>(v2o + off2));
    __builtin_nontemporal_store((v2f){(d0L - d1L) * KINV, (d0R - d1R) * KINV},
                                reinterpret_cast<v2f*>(d2o + off2));
}

extern "C" void kernel_launch(void* const* d_in, const int* in_sizes, int n_in,
                              void* d_out, int out_size, void* d_ws, size_t ws_size,
                              hipStream_t stream) {
    const float* x = (const float*)d_in[0];
    float* out = (float*)d_out;
    const int nimg = in_sizes[0] / (512 * 512);   // 96
    const int total_threads = nimg * 128 * 64;    // 786,432 threads (4x8 patch each)
    const int block = 256;
    const int grid = total_threads / block;       // 3072 blocks
    haar2_fused_kernel<<<grid, block, 0, stream>>>(x, out, nimg);
}